// Round 9
// baseline (525.206 us; speedup 1.0000x reference)
//
#include <hip/hip_runtime.h>
#include <hip/hip_fp16.h>
#include <math.h>

#define VOLN 256
#define N_ANG 16
#define DET_V 128
#define DET_U 128
#define DET_SP 5.0
#define DSI 400.0
#define DSD 800.0
#define N_STEP 192

// radius = sqrt(3)*256/2 ; t0 = DSI - radius ; dt = 2*radius/N_STEP
#define T0_F 178.29749663118372f
#define DT_F 2.3094010767585029f

// ---------------- fused fp32->fp16 convert + dual-layout (LDS transpose) ----------------
// A[z][y][x] = fp16(vol[z][y][x])   (x contiguous)
// B[z][x][y] = fp16(vol[z][y][x])   (y contiguous)
// block 256 = 32(tx) x 8(ty); grid (8,8,256): 32x32 (x,y) tile of slice z.
__global__ __launch_bounds__(256) void cvt_dual_kernel(const float* __restrict__ in,
                                                       __half* __restrict__ A,
                                                       __half* __restrict__ B) {
    __shared__ __half lds[32][34];   // stride 34 halves = 17 dwords -> conflict-free transpose
    int tx = threadIdx.x & 31, ty = threadIdx.x >> 5;
    int x0 = blockIdx.x << 5, y0 = blockIdx.y << 5, z = blockIdx.z;
    const float* src = in + (size_t)z * 65536;
    __half* a = A + (size_t)z * 65536;
    __half* b = B + (size_t)z * 65536;
    #pragma unroll
    for (int k = 0; k < 4; ++k) {
        int y = y0 + ty + k * 8;
        __half h = __float2half(src[y * 256 + x0 + tx]);
        a[y * 256 + x0 + tx] = h;
        lds[ty + k * 8][tx] = h;
    }
    __syncthreads();
    #pragma unroll
    for (int k = 0; k < 4; ++k) {
        int x = x0 + ty + k * 8;
        b[x * 256 + y0 + tx] = lds[tx][ty + k * 8];
    }
}

// ---------------- legacy single-layout conversion (fallback) ----------------
__global__ __launch_bounds__(256) void cvt_fp16_kernel(const float4* __restrict__ in,
                                                       uint2* __restrict__ out) {
    const int n4 = (VOLN * VOLN * VOLN) / 4;
    int stride = gridDim.x * blockDim.x;
    for (int i = blockIdx.x * blockDim.x + threadIdx.x; i < n4; i += stride) {
        float4 f = in[i];
        __half2 a = __floats2half2_rn(f.x, f.y);
        __half2 b = __floats2half2_rn(f.z, f.w);
        uint2 o;
        o.x = *reinterpret_cast<const unsigned int*>(&a);
        o.y = *reinterpret_cast<const unsigned int*>(&b);
        out[i] = o;
    }
}

// ---------------- generic fp16 trilerp over vol[256][256][256], dim2 contiguous ----------------
__device__ __forceinline__ float trilerp_g(const __half* __restrict__ vol,
                                           float p0, float p1, float p2) {
    float f0f = floorf(p0), f1f = floorf(p1), f2f = floorf(p2);
    int i0 = (int)f0f, i1 = (int)f1f, i2 = (int)f2f;
    float g0 = p0 - f0f, g1 = p1 - f1f, g2 = p2 - f2f;

    if (i0 >= 0 && i0 <= VOLN - 2 && i1 >= 0 && i1 <= VOLN - 2 && i2 >= 0 && i2 <= VOLN - 2) {
        const __half* base = vol + (((i0 << 8) + i1) << 8) + i2;
        float v000 = __half2float(base[0]);
        float v001 = __half2float(base[1]);
        float v010 = __half2float(base[VOLN]);
        float v011 = __half2float(base[VOLN + 1]);
        float v100 = __half2float(base[VOLN * VOLN]);
        float v101 = __half2float(base[VOLN * VOLN + 1]);
        float v110 = __half2float(base[VOLN * VOLN + VOLN]);
        float v111 = __half2float(base[VOLN * VOLN + VOLN + 1]);
        float c00 = fmaf(g2, v001 - v000, v000);
        float c01 = fmaf(g2, v011 - v010, v010);
        float c10 = fmaf(g2, v101 - v100, v100);
        float c11 = fmaf(g2, v111 - v110, v110);
        float c0 = fmaf(g1, c01 - c00, c00);
        float c1 = fmaf(g1, c11 - c10, c10);
        return fmaf(g0, c1 - c0, c0);
    }

    if (i0 < -1 || i0 > VOLN - 1 || i1 < -1 || i1 > VOLN - 1 || i2 < -1 || i2 > VOLN - 1)
        return 0.0f;

    float acc = 0.0f;
    #pragma unroll
    for (int d0 = 0; d0 < 2; ++d0) {
        int j0 = i0 + d0;
        if (j0 < 0 || j0 > VOLN - 1) continue;
        float w0 = d0 ? g0 : (1.0f - g0);
        #pragma unroll
        for (int d1 = 0; d1 < 2; ++d1) {
            int j1 = i1 + d1;
            if (j1 < 0 || j1 > VOLN - 1) continue;
            float w1 = d1 ? g1 : (1.0f - g1);
            #pragma unroll
            for (int d2 = 0; d2 < 2; ++d2) {
                int j2 = i2 + d2;
                if (j2 < 0 || j2 > VOLN - 1) continue;
                float w2 = d2 ? g2 : (1.0f - g2);
                float val = __half2float(vol[(((j0 << 8) + j1) << 8) + j2]);
                acc = fmaf(w0 * w1 * w2, val, acc);
            }
        }
    }
    return acc;
}

// ---------------- fp32 trilerp (fallback) ----------------
__device__ __forceinline__ float trilerp_f(const float* __restrict__ vol,
                                           float pz, float py, float px) {
    float z0f = floorf(pz), y0f = floorf(py), x0f = floorf(px);
    int z0 = (int)z0f, y0 = (int)y0f, x0 = (int)x0f;
    float fz = pz - z0f, fy = py - y0f, fx = px - x0f;

    if (z0 >= 0 && z0 <= VOLN - 2 && y0 >= 0 && y0 <= VOLN - 2 && x0 >= 0 && x0 <= VOLN - 2) {
        const float* base = vol + (((z0 << 8) + y0) << 8) + x0;
        float v000 = base[0], v001 = base[1];
        float v010 = base[VOLN], v011 = base[VOLN + 1];
        float v100 = base[VOLN * VOLN], v101 = base[VOLN * VOLN + 1];
        float v110 = base[VOLN * VOLN + VOLN], v111 = base[VOLN * VOLN + VOLN + 1];
        float c00 = fmaf(fx, v001 - v000, v000);
        float c01 = fmaf(fx, v011 - v010, v010);
        float c10 = fmaf(fx, v101 - v100, v100);
        float c11 = fmaf(fx, v111 - v110, v110);
        float c0 = fmaf(fy, c01 - c00, c00);
        float c1 = fmaf(fy, c11 - c10, c10);
        return fmaf(fz, c1 - c0, c0);
    }
    if (z0 < -1 || z0 > VOLN - 1 || y0 < -1 || y0 > VOLN - 1 || x0 < -1 || x0 > VOLN - 1)
        return 0.0f;
    float acc = 0.0f;
    #pragma unroll
    for (int dz = 0; dz < 2; ++dz) {
        int iz = z0 + dz;
        if (iz < 0 || iz > VOLN - 1) continue;
        float wz = dz ? fz : (1.0f - fz);
        #pragma unroll
        for (int dy = 0; dy < 2; ++dy) {
            int iy = y0 + dy;
            if (iy < 0 || iy > VOLN - 1) continue;
            float wy = dy ? fy : (1.0f - fy);
            #pragma unroll
            for (int dx = 0; dx < 2; ++dx) {
                int ix = x0 + dx;
                if (ix < 0 || ix > VOLN - 1) continue;
                float wx = dx ? fx : (1.0f - fx);
                acc = fmaf(wz * wy * wx, vol[(((iz << 8) + iy) << 8) + ix], acc);
            }
        }
    }
    return acc;
}

// ---------------- ray setup ----------------
struct Ray { float dirz, diry, dirx, bz, by, bx; float c, s; };

__device__ __forceinline__ Ray make_ray(int a, int u, int v) {
    double theta = (2.0 * M_PI / (double)N_ANG) * (double)a;
    double cth = cos(theta), sth = sin(theta);
    double uoff = ((double)u - (DET_U - 1) * 0.5) * DET_SP;
    double voff = ((double)v - (DET_V - 1) * 0.5) * DET_SP;

    double dzd = voff;
    double dyd = -DSD * sth + uoff * cth;
    double dxd = -DSD * cth - uoff * sth;
    double inv = 1.0 / sqrt(uoff * uoff + voff * voff + DSD * DSD);

    Ray r;
    r.dirz = (float)(dzd * inv);
    r.diry = (float)(dyd * inv);
    r.dirx = (float)(dxd * inv);
    const float half = (VOLN - 1) * 0.5f;
    r.bz = 0.0f + half;
    r.by = (float)(DSI * sth) + half;
    r.bx = (float)(DSI * cth) + half;
    r.c = (float)cth;
    r.s = (float)sth;
    return r;
}

// v-band XCD mapping (round-8 winner: FETCH 1.25GB -> 0.36GB).
// xcd = b & 7 (HW round-robin); XCD k gets contiguous v-band [16k,16k+16) of every angle.
__device__ __forceinline__ void decode_block(int b, int tid, int& a, int& u, int& v) {
    int xcd = b & 7;
    int j = b >> 3;            // 0..127
    a = j & 15;
    int sub = j >> 4;          // 0..7
    int vpair = (xcd << 3) + sub;
    u = tid & 127;
    v = (vpair << 1) + (tid >> 7);
}

// Dual-layout projection: pick the volume copy whose contiguous axis aligns with
// detector-u (the wave's lane axis). u_dir = (0, c, -s): |s|>=|c| -> lanes spread
// in x -> layout A (x contig); else lanes spread in y -> layout B (y contig).
__global__ __launch_bounds__(256) void cone_proj_h2_kernel(const __half* __restrict__ volA,
                                                           const __half* __restrict__ volB,
                                                           float* __restrict__ out) {
    int a, u, v;
    decode_block(blockIdx.x, threadIdx.x, a, u, v);
    Ray r = make_ray(a, u, v);

    bool useB = fabsf(r.c) > fabsf(r.s);
    const __half* vol = useB ? volB : volA;
    // generic axes: (d0,d1,d2) = A:(z,y,x)  B:(z,x,y)
    float dir1 = useB ? r.dirx : r.diry;
    float dir2 = useB ? r.diry : r.dirx;
    float b1   = useB ? r.bx   : r.by;
    float b2   = useB ? r.by   : r.bx;

    float acc = 0.0f;
    #pragma unroll 4
    for (int i = 0; i < N_STEP; ++i) {
        float t = fmaf((float)i + 0.5f, DT_F, T0_F);
        float p0 = fmaf(t, r.dirz, r.bz);
        float p1 = fmaf(t, dir1, b1);
        float p2 = fmaf(t, dir2, b2);
        acc += trilerp_g(vol, p0, p1, p2);
    }
    out[(a << 14) + (v << 7) + u] = acc * DT_F;
}

// Single-layout fp16 fallback (round-8 path)
__global__ __launch_bounds__(256) void cone_proj_h_kernel(const __half* __restrict__ vol,
                                                          float* __restrict__ out) {
    int a, u, v;
    decode_block(blockIdx.x, threadIdx.x, a, u, v);
    Ray r = make_ray(a, u, v);

    float acc = 0.0f;
    #pragma unroll 4
    for (int i = 0; i < N_STEP; ++i) {
        float t = fmaf((float)i + 0.5f, DT_F, T0_F);
        float p0 = fmaf(t, r.dirz, r.bz);
        float p1 = fmaf(t, r.diry, r.by);
        float p2 = fmaf(t, r.dirx, r.bx);
        acc += trilerp_g(vol, p0, p1, p2);
    }
    out[(a << 14) + (v << 7) + u] = acc * DT_F;
}

// fp32 fallback
__global__ __launch_bounds__(256) void cone_proj_f_kernel(const float* __restrict__ vol,
                                                          float* __restrict__ out) {
    int a, u, v;
    decode_block(blockIdx.x, threadIdx.x, a, u, v);
    Ray r = make_ray(a, u, v);

    float acc = 0.0f;
    #pragma unroll 4
    for (int i = 0; i < N_STEP; ++i) {
        float t = fmaf((float)i + 0.5f, DT_F, T0_F);
        float pz = fmaf(t, r.dirz, r.bz);
        float py = fmaf(t, r.diry, r.by);
        float px = fmaf(t, r.dirx, r.bx);
        acc += trilerp_f(vol, pz, py, px);
    }
    out[(a << 14) + (v << 7) + u] = acc * DT_F;
}

extern "C" void kernel_launch(void* const* d_in, const int* in_sizes, int n_in,
                              void* d_out, int out_size, void* d_ws, size_t ws_size,
                              hipStream_t stream) {
    const float* vol = (const float*)d_in[0];
    float* out = (float*)d_out;
    const int total = N_ANG * DET_V * DET_U;
    const size_t one = (size_t)VOLN * VOLN * VOLN * sizeof(__half);   // 32 MiB

    if (ws_size >= 2 * one) {
        __half* A = (__half*)d_ws;
        __half* B = (__half*)((char*)d_ws + one);
        dim3 cgrid(8, 8, VOLN);
        cvt_dual_kernel<<<cgrid, 256, 0, stream>>>(vol, A, B);
        cone_proj_h2_kernel<<<total / 256, 256, 0, stream>>>(A, B, out);
    } else if (ws_size >= one) {
        cvt_fp16_kernel<<<4096, 256, 0, stream>>>((const float4*)vol, (uint2*)d_ws);
        cone_proj_h_kernel<<<total / 256, 256, 0, stream>>>((const __half*)d_ws, out);
    } else {
        cone_proj_f_kernel<<<total / 256, 256, 0, stream>>>(vol, out);
    }
}